// Round 6
// baseline (269.303 us; speedup 1.0000x reference)
//
#include <hip/hip_runtime.h>
#include <cstdint>

// ---------------------------------------------------------------------------
// AttentionSelector: selected = softmax(query @ (x@Wk^T+bk)^T) @ x
// R13: 3-dispatch spine (prep / flash / combine), Part BF16. VERIFIED 259.3us
//      (flash 181.5, 256-thr, 2 blocks/CU, barrier-free).
// R15/R17: schedule-perturbing edits failed (absmax ~3.5): gfx950 VALU-write
//      -> v_permlane32_swap read hazard; bare inline asm gets no compiler
//      hazard mitigation. CONFIRMED by R18: s_nop-hardened plswap + perturbed
//      schedule PASSES.
// R16: setprio -> REGRESSED (210.7): at 2 waves/SIMD the co-wave's issue
//      stream IS the latency hiding.
// R18: 512-thr + barrier-every-8-tiles geometry -> flash 203.2 (REGRESSED):
//      barrier's vmcnt(0) drain kills prefetch depth and phase-locks waves.
//      Geometry reverted.
// R19: R13 geometry + hardened plswap + R15 pipe_step reorder (now safe):
//      k-pre -> mf(s0)+S0 -> mf(s1)+S1 -> PV0 -> PV1 -> x-reload. Doubles
//      xR issue-to-use distance (~250 -> ~500 cyc) to cover contended-L2
//      latency at PV0.
// ---------------------------------------------------------------------------

typedef __bf16    bf16x4 __attribute__((ext_vector_type(4)));
typedef __bf16    bf16x8 __attribute__((ext_vector_type(8)));
typedef _Float16  f16x4  __attribute__((ext_vector_type(4)));
typedef _Float16  f16x8  __attribute__((ext_vector_type(8)));
typedef float     f32x2  __attribute__((ext_vector_type(2)));
typedef float     f32x16 __attribute__((ext_vector_type(16)));

extern "C" __device__ float __ocml_native_exp2_f32(float);

#define NUM_PAIRS   65536
#define NUM_Q       8192
#define DIM         66
#define QPITCH      80        // Qh row pitch (f16)
#define KFT         2560      // Af f16 per 32-pair tile (5 kk x 512)
#define XFT         3072      // Xf bf16 per 32-pair tile (6 c x 512)
#define PARTP       68        // partial row pitch (bf16)
#define NS          16
#define NTILES      (NUM_PAIRS/32)   // 2048

__device__ __forceinline__ f32x16 mfma_bf16(bf16x8 a, bf16x8 b, f32x16 c) {
    return __builtin_amdgcn_mfma_f32_32x32x16_bf16(a, b, c, 0, 0, 0);
}
__device__ __forceinline__ f32x16 mfma_f16(f16x8 a, f16x8 b, f32x16 c) {
    return __builtin_amdgcn_mfma_f32_32x32x16_f16(a, b, c, 0, 0, 0);
}
// gfx950: exchange lanes 32..63 of a with lanes 0..31 of b.
// HAZARD-HARDENED (R18, verified): VALU-write -> permlane-read needs wait
// states; the compiler cannot see inside inline asm, so we carry our own
// s_nop on both sides. Keeps correctness schedule-independent.
__device__ __forceinline__ void plswap(unsigned &a, unsigned &b) {
    asm volatile("s_nop 1\n\t"
                 "v_permlane32_swap_b32 %0, %1\n\t"
                 "s_nop 1"
                 : "+v"(a), "+v"(b));
}
__device__ __forceinline__ unsigned packbf(float a, float b) {
    union { __bf16 h[2]; unsigned u; } t;
    t.h[0] = (__bf16)a; t.h[1] = (__bf16)b;
    return t.u;
}
union U4 { unsigned u[4]; bf16x8 v; };

// Sᵀ C-tile (col=query l31, row(pair)=(r&3)+8*(r>>2)+4h) -> exp2 -> two PV
// A-frags (par0: pairs 0..15, par1: 16..31) via permlane32_swap.
__device__ __forceinline__ void makefrags(const f32x16 &s, U4 *f) {
    float P[16];
    #pragma unroll
    for (int r = 0; r < 16; ++r) P[r] = __ocml_native_exp2_f32(s[r]);
    unsigned E0 = packbf(P[0],  P[1]),  E1 = packbf(P[2],  P[3]);
    unsigned F0 = packbf(P[4],  P[5]),  F1 = packbf(P[6],  P[7]);
    plswap(E0, F0); plswap(E1, F1);
    f[0].u[0] = E0; f[0].u[1] = E1; f[0].u[2] = F0; f[0].u[3] = F1;
    unsigned G0 = packbf(P[8],  P[9]),  G1 = packbf(P[10], P[11]);
    unsigned H0 = packbf(P[12], P[13]), H1 = packbf(P[14], P[15]);
    plswap(G0, H0); plswap(G1, H1);
    f[1].u[0] = G0; f[1].u[1] = G1; f[1].u[2] = H0; f[1].u[3] = H1;
}

// One pipelined flash step for tile t.
// R19 order: k-pre, mf(s0), S0, mf(s1), S1, PV0, PV1, x-reload — maximizes
// the distance from the x-issue (end of previous step) to PV0 (first xR use).
__device__ __forceinline__ void pipe_step(
    int t, int tiles, const _Float16* __restrict__ kf, const __bf16* __restrict__ xf,
    f16x8 (&kPre)[5], const f16x8 (&kNext)[5], bf16x8 (&xR)[6],
    const f16x8 (&aQ)[2][5], f32x16 &s0, f32x16 &s1, f32x16 (&o)[2][3]) {

    {   // prefetch k(t+2) into the dead buffer
        long tk = (t + 2 < tiles) ? (long)(t + 2) : (long)(tiles - 1);
        const _Float16* kp = kf + tk * KFT;
        #pragma unroll
        for (int kk = 0; kk < 5; ++kk) kPre[kk] = *(const f16x8*)(kp + kk * 512);
    }
    U4 f0[2];
    makefrags(s0, f0);
    {
        f32x16 ns = {};
        #pragma unroll
        for (int kk = 0; kk < 5; ++kk) ns = mfma_f16(kNext[kk], aQ[0][kk], ns);
        s0 = ns;
    }
    U4 f1[2];
    makefrags(s1, f1);
    {
        f32x16 ns = {};
        #pragma unroll
        for (int kk = 0; kk < 5; ++kk) ns = mfma_f16(kNext[kk], aQ[1][kk], ns);
        s1 = ns;
    }
    #pragma unroll
    for (int par = 0; par < 2; ++par)
        #pragma unroll
        for (int dt = 0; dt < 3; ++dt)
            o[0][dt] = mfma_bf16(f0[par].v, xR[par * 3 + dt], o[0][dt]);
    #pragma unroll
    for (int par = 0; par < 2; ++par)
        #pragma unroll
        for (int dt = 0; dt < 3; ++dt)
            o[1][dt] = mfma_bf16(f1[par].v, xR[par * 3 + dt], o[1][dt]);

    {   // reload x with tile t+1 (last use was PV1 above)
        long tx = (t + 1 < tiles) ? (long)(t + 1) : (long)(tiles - 1);
        const __bf16* xp = xf + tx * XFT;
        #pragma unroll
        for (int c = 0; c < 6; ++c) xR[c] = *(const bf16x8*)(xp + c * 512);
    }
}

// ---------------------------------------------------------------------------
// Prep: blocks 0..511 -> 128 pairs each: x -> Af (f16 S-frags) + Xf (bf16 PV
//       frags, ones-trick for row 66). blocks 512..575 -> 128 queries each:
//       Qh = (Wk^T q)*log2e via mfma f16.
// ---------------------------------------------------------------------------
#define PAP 104   // LDS pitch (f16)
__global__ __launch_bounds__(256) void prep_kernel(
    const float* __restrict__ x, const float* __restrict__ query,
    const float* __restrict__ Wk,
    unsigned short* __restrict__ Af_u, unsigned short* __restrict__ Xf_u,
    unsigned short* __restrict__ Qh_u) {
    const int tid = threadIdx.x;
    const int lane = tid & 63, w = tid >> 6;
    const int l31 = lane & 31, h = lane >> 5;

    if (blockIdx.x >= 512) {
        // ---- query side: Qh = (Wk^T q) * log2e via mfma ----
        __shared__ _Float16 sq[128 * PAP];    // query rows f16, pads 0
        __shared__ _Float16 sWT[96 * PAP];    // sWT[e][d] = Wk[d][e]*log2e, pads 0
        _Float16* Qh = (_Float16*)Qh_u;
        const long q0 = (long)(blockIdx.x - 512) * 128;

        for (int i = tid; i < 128 * PAP / 2; i += 256) ((unsigned*)sq)[i] = 0u;
        for (int i = tid; i < 96 * PAP / 2; i += 256)  ((unsigned*)sWT)[i] = 0u;
        __syncthreads();

        for (int i = tid; i < 128 * 33; i += 256) {       // f32x2 loads
            int r = i / 33, c2 = (i % 33) * 2;
            f32x2 v = *(const f32x2*)&query[(q0 + r) * DIM + c2];
            sq[r * PAP + c2]     = (_Float16)v.x;
            sq[r * PAP + c2 + 1] = (_Float16)v.y;
        }
        for (int i = tid; i < DIM * 33; i += 256) {       // Wk transposed, scaled
            int d = i / 33, e2 = (i % 33) * 2;
            f32x2 v = *(const f32x2*)&Wk[d * DIM + e2];
            sWT[e2 * PAP + d]       = (_Float16)(v.x * 1.4426950408889634f);
            sWT[(e2 + 1) * PAP + d] = (_Float16)(v.y * 1.4426950408889634f);
        }
        __syncthreads();

        #pragma unroll
        for (int nt = 0; nt < 3; ++nt) {
            f32x16 acc = {};
            #pragma unroll
            for (int kk = 0; kk < 6; ++kk) {
                f16x8 a = *(const f16x8*)&sq[(w * 32 + l31) * PAP + kk * 16 + h * 8];
                f16x8 b = *(const f16x8*)&sWT[(nt * 32 + l31) * PAP + kk * 16 + h * 8];
                acc = mfma_f16(a, b, acc);
            }
            int c = nt * 32 + l31;
            if (c < QPITCH) {
                #pragma unroll
                for (int r = 0; r < 16; ++r) {
                    int row = (r & 3) + 8 * (r >> 2) + 4 * h;
                    Qh[(q0 + w * 32 + row) * QPITCH + c] = (_Float16)acc[r];
                }
            }
        }
        return;
    }

    // ---- pair side: x -> Af + Xf ----
    _Float16* Af = (_Float16*)Af_u;
    __bf16*   Xf = (__bf16*)Xf_u;
    __shared__ _Float16 sxh[128 * PAP];   // cols: 0..65 = x, 66 = 1.0, 67.. = 0
    const long n0 = (long)blockIdx.x * 128;

    for (int i = tid; i < 128 * PAP / 2; i += 256) ((unsigned*)sxh)[i] = 0u;
    __syncthreads();
    for (int i = tid; i < 128 * 33; i += 256) {
        int r = i / 33, c2 = (i % 33) * 2;
        f32x2 v = *(const f32x2*)&x[(n0 + r) * DIM + c2];
        sxh[r * PAP + c2]     = (_Float16)v.x;
        sxh[r * PAP + c2 + 1] = (_Float16)v.y;
    }
    for (int r = tid; r < 128; r += 256) sxh[r * PAP + DIM] = (_Float16)1.0f;
    __syncthreads();

    // Af emission: [tile][kk][lane][8] (col 66 = 1 harmless: Qh cols 66+ are 0)
    for (int i = 0; i < 5; ++i) {
        int slot = i * 256 + tid;
        int tt = slot / 320, rem = slot % 320;
        int kk = rem / 64, l = rem % 64;
        const _Float16* src = &sxh[(32 * tt + (l & 31)) * PAP + kk * 16 + (l >> 5) * 8];
        f16x4 lo = *(const f16x4*)src;
        f16x4 hi = *(const f16x4*)(src + 4);
        f16x8 v = __builtin_shufflevector(lo, hi, 0, 1, 2, 3, 4, 5, 6, 7);
        *(f16x8*)&Af[((long)blockIdx.x * 4 + tt) * KFT + kk * 512 + l * 8] = v;
    }
    // Xf emission (branch-free): [tile][c=par*3+dt][lane][8] = X^T[d][pair]
    for (int i = 0; i < 6; ++i) {
        int slot = i * 256 + tid;
        int tt = slot / 384, rem = slot % 384;
        int c = rem / 64, l = rem % 64;
        int dt = c % 3, par = c / 3;
        int d = 32 * dt + (l & 31);
        int p0 = 32 * tt + 16 * par + 8 * (l >> 5);
        bf16x8 v;
        #pragma unroll
        for (int j = 0; j < 8; ++j)
            v[j] = (__bf16)(float)sxh[(p0 + j) * PAP + d];
        *(bf16x8*)&Xf[((long)blockIdx.x * 4 + tt) * XFT + c * 512 + l * 8] = v;
    }
}

// ---------------------------------------------------------------------------
// Flash: grid = 32 qblocks * NS; 256 thr = 4 waves x 64 q (qt=2). No LDS, no
// barriers. S carried across iterations; K reg-dbuf, X single-buffer.
// Partials written as BF16, layout [q][NS][68]; col 66 = denominator.
// ---------------------------------------------------------------------------
__global__ __launch_bounds__(256, 2) void flash_kernel(
    const unsigned short* __restrict__ Qh_u, const unsigned short* __restrict__ Af_u,
    const unsigned short* __restrict__ Xf_u, unsigned short* __restrict__ Part_u) {
    const _Float16* Qh = (const _Float16*)Qh_u;
    const _Float16* Af = (const _Float16*)Af_u;
    const __bf16*   Xf = (const __bf16*)Xf_u;
    __bf16* Part = (__bf16*)Part_u;

    const int tid = threadIdx.x;
    const int lane = tid & 63, wave = tid >> 6;
    const int l31 = lane & 31, h = lane >> 5;
    const int qb = blockIdx.x / NS, ns = blockIdx.x % NS;
    const int tiles = NTILES / NS;            // 128
    const int qbase = qb * 256 + wave * 64;

    const _Float16* kf = Af + (long)(ns * tiles) * KFT + lane * 8;
    const __bf16*   xf = Xf + (long)(ns * tiles) * XFT + lane * 8;

    f16x8 aQ[2][5];
    #pragma unroll
    for (int qt = 0; qt < 2; ++qt)
        #pragma unroll
        for (int kk = 0; kk < 5; ++kk)
            aQ[qt][kk] = *(const f16x8*)&Qh[(long)(qbase + qt * 32 + l31) * QPITCH + kk * 16 + h * 8];

    f32x16 o[2][3] = {};
    f16x8  kA[5], kB[5];
    bf16x8 xR[6];
    f32x16 s0, s1;

    #pragma unroll
    for (int kk = 0; kk < 5; ++kk) kA[kk] = *(const f16x8*)(kf + kk * 512);
    #pragma unroll
    for (int c = 0; c < 6; ++c)    xR[c]  = *(const bf16x8*)(xf + c * 512);
    #pragma unroll
    for (int kk = 0; kk < 5; ++kk) kB[kk] = *(const f16x8*)(kf + KFT + kk * 512);
    {
        f32x16 a = {}, b = {};
        #pragma unroll
        for (int kk = 0; kk < 5; ++kk) {
            a = mfma_f16(kA[kk], aQ[0][kk], a);
            b = mfma_f16(kA[kk], aQ[1][kk], b);
        }
        s0 = a; s1 = b;
    }

    for (int t = 0; t < tiles; t += 2) {
        pipe_step(t,     tiles, kf, xf, kA, kB, xR, aQ, s0, s1, o);
        pipe_step(t + 1, tiles, kf, xf, kB, kA, xR, aQ, s0, s1, o);
    }

    // epilogue: bf16 partials [q][NS][68]; col 66 = denominator
    #pragma unroll
    for (int qt = 0; qt < 2; ++qt)
        #pragma unroll
        for (int dt = 0; dt < 3; ++dt)
            #pragma unroll
            for (int r = 0; r < 16; ++r) {
                int row = (r & 3) + 8 * (r >> 2) + 4 * h;
                int q = qbase + qt * 32 + row;
                int d = dt * 32 + l31;
                if (d < DIM + 1)
                    Part[((long)q * NS + ns) * PARTP + d] = (__bf16)o[qt][dt][r];
            }
}

// ---------------------------------------------------------------------------
// Combine: out[q][d] = sum_s Part[q][s][d] / sum_s Part[q][s][66]
// Part rows for one q are contiguous (NS*136 B).
// ---------------------------------------------------------------------------
__global__ __launch_bounds__(256) void combine_kernel(
    const unsigned short* __restrict__ Part_u, float* __restrict__ out) {
    const __bf16* Part = (const __bf16*)Part_u;
    int q = blockIdx.x * 2 + (threadIdx.x >> 7);
    int d = threadIdx.x & 127;
    if (d >= DIM) return;
    const __bf16* base = Part + (long)q * NS * PARTP;
    float num = 0.f, den = 0.f;
    #pragma unroll 4
    for (int s = 0; s < NS; ++s) {
        num += (float)base[s * PARTP + d];
        den += (float)base[s * PARTP + DIM];
    }
    out[(long)q * DIM + d] = num / den;
}

// ---------------------------------------------------------------------------
// Workspace: Qh @0 (1,310,720 B) ; Af @1,310,720 (10,485,760 B) ;
//            Xf @11,796,480 (12,582,912 B) ; Part @24,379,392 (17,825,792 B)
// ---------------------------------------------------------------------------
extern "C" void kernel_launch(void* const* d_in, const int* in_sizes, int n_in,
                              void* d_out, int out_size, void* d_ws, size_t ws_size,
                              hipStream_t stream) {
    const float* x     = (const float*)d_in[0];
    const float* query = (const float*)d_in[1];
    const float* Wk    = (const float*)d_in[2];
    float* out = (float*)d_out;
    char* ws = (char*)d_ws;

    unsigned short* Qh   = (unsigned short*)(ws + 0);
    unsigned short* Af   = (unsigned short*)(ws + 1310720);
    unsigned short* Xf   = (unsigned short*)(ws + 11796480);
    unsigned short* Part = (unsigned short*)(ws + 24379392);

    prep_kernel<<<512 + NUM_Q / 128, 256, 0, stream>>>(x, query, Wk, Af, Xf, Qh);
    flash_kernel<<<(NUM_Q / 256) * NS, 256, 0, stream>>>(Qh, Af, Xf, Part);
    combine_kernel<<<NUM_Q / 2, 256, 0, stream>>>(Part, out);
}

// Round 7
// 249.644 us; speedup vs baseline: 1.0787x; 1.0787x over previous
//
#include <hip/hip_runtime.h>
#include <cstdint>

// ---------------------------------------------------------------------------
// AttentionSelector: selected = softmax(query @ (x@Wk^T+bk)^T) @ x
// R13: 3-dispatch spine, Part BF16. VERIFIED 259.3us (flash 181.5).
// R15/R17: schedule edits failed -> gfx950 VALU-write->permlane32_swap hazard
//      in bare inline asm. CONFIRMED+FIXED by R18's s_nop-hardened plswap.
// R16: setprio REGRESSED (210.7): at 2 waves/SIMD co-wave issue IS the hiding.
// R18: 512-thr + bare barriers REGRESSED (203.2): vmcnt(0) drain at barrier
//      killed prefetch depth + phase-locked waves.
// R19: pipe reorder (more xR distance) NEUTRAL-NEG (189.9) -> xR latency not
//      the stall. s_nop hardening costs ~2% (keep: correctness insurance).
// R20: LDS chunk staging (2-tile chunks, double-buffered, 44KB/block):
//      each block stages the Af/Xf stream ONCE via global_load_lds and all
//      4 waves consume via ds_read_b128 (2-way bank = free). Kills the 4x
//      redundant per-wave global stream (~53 B/cyc/CU -> 13). Staging is
//      issued a full chunk (~2800 cyc) before the barrier that drains it, so
//      R18's drain cost does not apply. K-chunks offset by one tile
//      ({2c+1,2c+2}) preserve the verified S-carry pipeline exactly.
// ---------------------------------------------------------------------------

typedef __bf16    bf16x4 __attribute__((ext_vector_type(4)));
typedef __bf16    bf16x8 __attribute__((ext_vector_type(8)));
typedef _Float16  f16x4  __attribute__((ext_vector_type(4)));
typedef _Float16  f16x8  __attribute__((ext_vector_type(8)));
typedef float     f32x2  __attribute__((ext_vector_type(2)));
typedef float     f32x16 __attribute__((ext_vector_type(16)));

extern "C" __device__ float __ocml_native_exp2_f32(float);

#define NUM_PAIRS   65536
#define NUM_Q       8192
#define DIM         66
#define QPITCH      80        // Qh row pitch (f16)
#define KFT         2560      // Af f16 per 32-pair tile (5 kk x 512)
#define XFT         3072      // Xf bf16 per 32-pair tile (6 c x 512)
#define PARTP       68        // partial row pitch (bf16)
#define NS          16
#define NTILES      (NUM_PAIRS/32)   // 2048

#define KBYTES      5120      // Af bytes per tile
#define XBYTES      6144      // Xf bytes per tile
#define CHUNK_K     (2*KBYTES)          // 10240
#define CHUNK_X     (2*XBYTES)          // 12288
#define CHUNK_BYTES (CHUNK_K+CHUNK_X)   // 22528

__device__ __forceinline__ f32x16 mfma_bf16(bf16x8 a, bf16x8 b, f32x16 c) {
    return __builtin_amdgcn_mfma_f32_32x32x16_bf16(a, b, c, 0, 0, 0);
}
__device__ __forceinline__ f32x16 mfma_f16(f16x8 a, f16x8 b, f32x16 c) {
    return __builtin_amdgcn_mfma_f32_32x32x16_f16(a, b, c, 0, 0, 0);
}
// gfx950: exchange lanes 32..63 of a with lanes 0..31 of b.
// HAZARD-HARDENED (R18, verified): VALU-write -> permlane-read needs wait
// states; compiler can't see inside inline asm, so carry our own s_nop.
__device__ __forceinline__ void plswap(unsigned &a, unsigned &b) {
    asm volatile("s_nop 1\n\t"
                 "v_permlane32_swap_b32 %0, %1\n\t"
                 "s_nop 1"
                 : "+v"(a), "+v"(b));
}
__device__ __forceinline__ unsigned packbf(float a, float b) {
    union { __bf16 h[2]; unsigned u; } t;
    t.h[0] = (__bf16)a; t.h[1] = (__bf16)b;
    return t.u;
}
union U4 { unsigned u[4]; bf16x8 v; };

// async global->LDS, 16B per lane, linear dest (wave base + lane*16)
__device__ __forceinline__ void gload16(const void* g, void* l) {
    __builtin_amdgcn_global_load_lds(
        (const __attribute__((address_space(1))) unsigned int*)g,
        (__attribute__((address_space(3))) unsigned int*)l,
        16, 0, 0);
}

// Sᵀ C-tile (col=query l31, row(pair)=(r&3)+8*(r>>2)+4h) -> exp2 -> two PV
// A-frags (par0: pairs 0..15, par1: 16..31) via permlane32_swap (verified).
__device__ __forceinline__ void makefrags(const f32x16 &s, U4 *f) {
    float P[16];
    #pragma unroll
    for (int r = 0; r < 16; ++r) P[r] = __ocml_native_exp2_f32(s[r]);
    unsigned E0 = packbf(P[0],  P[1]),  E1 = packbf(P[2],  P[3]);
    unsigned F0 = packbf(P[4],  P[5]),  F1 = packbf(P[6],  P[7]);
    plswap(E0, F0); plswap(E1, F1);
    f[0].u[0] = E0; f[0].u[1] = E1; f[0].u[2] = F0; f[0].u[3] = F1;
    unsigned G0 = packbf(P[8],  P[9]),  G1 = packbf(P[10], P[11]);
    unsigned H0 = packbf(P[12], P[13]), H1 = packbf(P[14], P[15]);
    plswap(G0, H0); plswap(G1, H1);
    f[1].u[0] = G0; f[1].u[1] = G1; f[1].u[2] = H0; f[1].u[3] = H1;
}

// ---------------------------------------------------------------------------
// Prep: blocks 0..511 -> 128 pairs each: x -> Af (f16 S-frags) + Xf (bf16 PV
//       frags, ones-trick for row 66). blocks 512..575 -> 128 queries each:
//       Qh = (Wk^T q)*log2e via mfma f16.   (unchanged, verified)
// ---------------------------------------------------------------------------
#define PAP 104   // LDS pitch (f16)
__global__ __launch_bounds__(256) void prep_kernel(
    const float* __restrict__ x, const float* __restrict__ query,
    const float* __restrict__ Wk,
    unsigned short* __restrict__ Af_u, unsigned short* __restrict__ Xf_u,
    unsigned short* __restrict__ Qh_u) {
    const int tid = threadIdx.x;
    const int lane = tid & 63, w = tid >> 6;
    const int l31 = lane & 31, h = lane >> 5;

    if (blockIdx.x >= 512) {
        // ---- query side: Qh = (Wk^T q) * log2e via mfma ----
        __shared__ _Float16 sq[128 * PAP];    // query rows f16, pads 0
        __shared__ _Float16 sWT[96 * PAP];    // sWT[e][d] = Wk[d][e]*log2e, pads 0
        _Float16* Qh = (_Float16*)Qh_u;
        const long q0 = (long)(blockIdx.x - 512) * 128;

        for (int i = tid; i < 128 * PAP / 2; i += 256) ((unsigned*)sq)[i] = 0u;
        for (int i = tid; i < 96 * PAP / 2; i += 256)  ((unsigned*)sWT)[i] = 0u;
        __syncthreads();

        for (int i = tid; i < 128 * 33; i += 256) {       // f32x2 loads
            int r = i / 33, c2 = (i % 33) * 2;
            f32x2 v = *(const f32x2*)&query[(q0 + r) * DIM + c2];
            sq[r * PAP + c2]     = (_Float16)v.x;
            sq[r * PAP + c2 + 1] = (_Float16)v.y;
        }
        for (int i = tid; i < DIM * 33; i += 256) {       // Wk transposed, scaled
            int d = i / 33, e2 = (i % 33) * 2;
            f32x2 v = *(const f32x2*)&Wk[d * DIM + e2];
            sWT[e2 * PAP + d]       = (_Float16)(v.x * 1.4426950408889634f);
            sWT[(e2 + 1) * PAP + d] = (_Float16)(v.y * 1.4426950408889634f);
        }
        __syncthreads();

        #pragma unroll
        for (int nt = 0; nt < 3; ++nt) {
            f32x16 acc = {};
            #pragma unroll
            for (int kk = 0; kk < 6; ++kk) {
                f16x8 a = *(const f16x8*)&sq[(w * 32 + l31) * PAP + kk * 16 + h * 8];
                f16x8 b = *(const f16x8*)&sWT[(nt * 32 + l31) * PAP + kk * 16 + h * 8];
                acc = mfma_f16(a, b, acc);
            }
            int c = nt * 32 + l31;
            if (c < QPITCH) {
                #pragma unroll
                for (int r = 0; r < 16; ++r) {
                    int row = (r & 3) + 8 * (r >> 2) + 4 * h;
                    Qh[(q0 + w * 32 + row) * QPITCH + c] = (_Float16)acc[r];
                }
            }
        }
        return;
    }

    // ---- pair side: x -> Af + Xf ----
    _Float16* Af = (_Float16*)Af_u;
    __bf16*   Xf = (__bf16*)Xf_u;
    __shared__ _Float16 sxh[128 * PAP];   // cols: 0..65 = x, 66 = 1.0, 67.. = 0
    const long n0 = (long)blockIdx.x * 128;

    for (int i = tid; i < 128 * PAP / 2; i += 256) ((unsigned*)sxh)[i] = 0u;
    __syncthreads();
    for (int i = tid; i < 128 * 33; i += 256) {
        int r = i / 33, c2 = (i % 33) * 2;
        f32x2 v = *(const f32x2*)&x[(n0 + r) * DIM + c2];
        sxh[r * PAP + c2]     = (_Float16)v.x;
        sxh[r * PAP + c2 + 1] = (_Float16)v.y;
    }
    for (int r = tid; r < 128; r += 256) sxh[r * PAP + DIM] = (_Float16)1.0f;
    __syncthreads();

    // Af emission: [tile][kk][lane][8] (col 66 = 1 harmless: Qh cols 66+ are 0)
    for (int i = 0; i < 5; ++i) {
        int slot = i * 256 + tid;
        int tt = slot / 320, rem = slot % 320;
        int kk = rem / 64, l = rem % 64;
        const _Float16* src = &sxh[(32 * tt + (l & 31)) * PAP + kk * 16 + (l >> 5) * 8];
        f16x4 lo = *(const f16x4*)src;
        f16x4 hi = *(const f16x4*)(src + 4);
        f16x8 v = __builtin_shufflevector(lo, hi, 0, 1, 2, 3, 4, 5, 6, 7);
        *(f16x8*)&Af[((long)blockIdx.x * 4 + tt) * KFT + kk * 512 + l * 8] = v;
    }
    // Xf emission (branch-free): [tile][c=par*3+dt][lane][8] = X^T[d][pair]
    for (int i = 0; i < 6; ++i) {
        int slot = i * 256 + tid;
        int tt = slot / 384, rem = slot % 384;
        int c = rem / 64, l = rem % 64;
        int dt = c % 3, par = c / 3;
        int d = 32 * dt + (l & 31);
        int p0 = 32 * tt + 16 * par + 8 * (l >> 5);
        bf16x8 v;
        #pragma unroll
        for (int j = 0; j < 8; ++j)
            v[j] = (__bf16)(float)sxh[(p0 + j) * PAP + d];
        *(bf16x8*)&Xf[((long)blockIdx.x * 4 + tt) * XFT + c * 512 + l * 8] = v;
    }
}

// ---------------------------------------------------------------------------
// Flash (R20): grid = 32 qblocks * NS; 256 thr = 4 waves x 64 q (qt=2).
// 2-tile chunks staged once per block into double-buffered LDS (44KB) via
// global_load_lds; all 4 waves consume via ds_read_b128. K-chunk(c) =
// {K(2c+1),K(2c+2)} (S-carry needs K one tile ahead); X-chunk(c) =
// {X(2c),X(2c+1)}. One barrier per chunk; staging issued a full chunk ahead.
// Partials BF16, layout [q][NS][68]; col 66 = denominator.
// ---------------------------------------------------------------------------
__global__ __launch_bounds__(256, 2) void flash_kernel(
    const unsigned short* __restrict__ Qh_u, const unsigned short* __restrict__ Af_u,
    const unsigned short* __restrict__ Xf_u, unsigned short* __restrict__ Part_u) {
    const _Float16* Qh = (const _Float16*)Qh_u;
    const _Float16* Af = (const _Float16*)Af_u;
    const __bf16*   Xf = (const __bf16*)Xf_u;
    __bf16* Part = (__bf16*)Part_u;

    const int tid = threadIdx.x;
    const int lane = tid & 63, wave = tid >> 6;
    const int l31 = lane & 31, h = lane >> 5;
    const int qb = blockIdx.x / NS, ns = blockIdx.x % NS;
    const int tiles = NTILES / NS;            // 128
    const int qbase = qb * 256 + wave * 64;

    const char* Kg = (const char*)(Af + (long)(ns * tiles) * KFT);
    const char* Xg = (const char*)(Xf + (long)(ns * tiles) * XFT);

    __shared__ __align__(16) char smem[2 * CHUNK_BYTES];   // 45056 B

    // stage chunk m into buffer parity pb: K{2m+1,2m+2}, X{2m,2m+1}
    auto stage = [&](int m, int pb) {
        char* bK = smem + pb * CHUNK_BYTES;
        char* bX = bK + CHUNK_K;
        long ka = (2 * m + 1 < tiles) ? 2 * m + 1 : tiles - 1;
        long kb = (2 * m + 2 < tiles) ? 2 * m + 2 : tiles - 1;
        long xa = (2 * m     < tiles) ? 2 * m     : tiles - 1;
        long xb = (2 * m + 1 < tiles) ? 2 * m + 1 : tiles - 1;
        gload16(Kg + ka * KBYTES + tid * 16, bK + tid * 16);
        gload16(Kg + kb * KBYTES + tid * 16, bK + KBYTES + tid * 16);
        gload16(Xg + xa * XBYTES + tid * 16, bX + tid * 16);
        gload16(Xg + xb * XBYTES + tid * 16, bX + XBYTES + tid * 16);
        if (tid < 64) {          // wave 0: K tail 1KB each
            gload16(Kg + ka * KBYTES + 4096 + tid * 16, bK + 4096 + tid * 16);
            gload16(Kg + kb * KBYTES + 4096 + tid * 16, bK + KBYTES + 4096 + tid * 16);
        }
        if (tid < 128) {         // waves 0,1: X tail 2KB each
            gload16(Xg + xa * XBYTES + 4096 + tid * 16, bX + 4096 + tid * 16);
            gload16(Xg + xb * XBYTES + 4096 + tid * 16, bX + XBYTES + 4096 + tid * 16);
        }
    };

    f16x8 aQ[2][5];
    #pragma unroll
    for (int qt = 0; qt < 2; ++qt)
        #pragma unroll
        for (int kk = 0; kk < 5; ++kk)
            aQ[qt][kk] = *(const f16x8*)&Qh[(long)(qbase + qt * 32 + l31) * QPITCH + kk * 16 + h * 8];

    f32x16 o[2][3] = {};
    f32x16 s0, s1;

    // prologue: stage chunk 0; direct-load K(0) for the initial scores
    stage(0, 0);
    {
        f16x8 kA[5];
        #pragma unroll
        for (int kk = 0; kk < 5; ++kk)
            kA[kk] = *(const f16x8*)(Kg + kk * 1024 + lane * 16);
        f32x16 a = {}, b = {};
        #pragma unroll
        for (int kk = 0; kk < 5; ++kk) {
            a = mfma_f16(kA[kk], aQ[0][kk], a);
            b = mfma_f16(kA[kk], aQ[1][kk], b);
        }
        s0 = a; s1 = b;
    }
    __syncthreads();   // staging of chunk 0 visible

    for (int c = 0; c < tiles / 2; ++c) {
        if (c + 1 < tiles / 2) stage(c + 1, (c + 1) & 1);
        const char* bK = smem + (c & 1) * CHUNK_BYTES;
        const char* bX = bK + CHUNK_K;
        #pragma unroll
        for (int p = 0; p < 2; ++p) {
            f16x8 kR[5];
            #pragma unroll
            for (int kk = 0; kk < 5; ++kk)
                kR[kk] = *(const f16x8*)(bK + p * KBYTES + kk * 1024 + lane * 16);
            bf16x8 xR[6];
            #pragma unroll
            for (int cc = 0; cc < 6; ++cc)
                xR[cc] = *(const bf16x8*)(bX + p * XBYTES + cc * 1024 + lane * 16);

            U4 f0[2];
            makefrags(s0, f0);
            {
                f32x16 nsv = {};
                #pragma unroll
                for (int kk = 0; kk < 5; ++kk) nsv = mfma_f16(kR[kk], aQ[0][kk], nsv);
                s0 = nsv;
            }
            #pragma unroll
            for (int par = 0; par < 2; ++par)
                #pragma unroll
                for (int dt = 0; dt < 3; ++dt)
                    o[0][dt] = mfma_bf16(f0[par].v, xR[par * 3 + dt], o[0][dt]);

            U4 f1[2];
            makefrags(s1, f1);
            {
                f32x16 nsv = {};
                #pragma unroll
                for (int kk = 0; kk < 5; ++kk) nsv = mfma_f16(kR[kk], aQ[1][kk], nsv);
                s1 = nsv;
            }
            #pragma unroll
            for (int par = 0; par < 2; ++par)
                #pragma unroll
                for (int dt = 0; dt < 3; ++dt)
                    o[1][dt] = mfma_bf16(f1[par].v, xR[par * 3 + dt], o[1][dt]);
        }
        __syncthreads();   // chunk c reads done; chunk c+1 staging landed
    }

    // epilogue: bf16 partials [q][NS][68]; col 66 = denominator
    #pragma unroll
    for (int qt = 0; qt < 2; ++qt)
        #pragma unroll
        for (int dt = 0; dt < 3; ++dt)
            #pragma unroll
            for (int r = 0; r < 16; ++r) {
                int row = (r & 3) + 8 * (r >> 2) + 4 * h;
                int q = qbase + qt * 32 + row;
                int d = dt * 32 + l31;
                if (d < DIM + 1)
                    Part[((long)q * NS + ns) * PARTP + d] = (__bf16)o[qt][dt][r];
            }
}

// ---------------------------------------------------------------------------
// Combine: out[q][d] = sum_s Part[q][s][d] / sum_s Part[q][s][66]
// Part rows for one q are contiguous (NS*136 B).
// ---------------------------------------------------------------------------
__global__ __launch_bounds__(256) void combine_kernel(
    const unsigned short* __restrict__ Part_u, float* __restrict__ out) {
    const __bf16* Part = (const __bf16*)Part_u;
    int q = blockIdx.x * 2 + (threadIdx.x >> 7);
    int d = threadIdx.x & 127;
    if (d >= DIM) return;
    const __bf16* base = Part + (long)q * NS * PARTP;
    float num = 0.f, den = 0.f;
    #pragma unroll 4
    for (int s = 0; s < NS; ++s) {
        num += (float)base[s * PARTP + d];
        den += (float)base[s * PARTP + DIM];
    }
    out[(long)q * DIM + d] = num / den;
}

// ---------------------------------------------------------------------------
// Workspace: Qh @0 (1,310,720 B) ; Af @1,310,720 (10,485,760 B) ;
//            Xf @11,796,480 (12,582,912 B) ; Part @24,379,392 (17,825,792 B)
// ---------------------------------------------------------------------------
extern "C" void kernel_launch(void* const* d_in, const int* in_sizes, int n_in,
                              void* d_out, int out_size, void* d_ws, size_t ws_size,
                              hipStream_t stream) {
    const float* x     = (const float*)d_in[0];
    const float* query = (const float*)d_in[1];
    const float* Wk    = (const float*)d_in[2];
    float* out = (float*)d_out;
    char* ws = (char*)d_ws;

    unsigned short* Qh   = (unsigned short*)(ws + 0);
    unsigned short* Af   = (unsigned short*)(ws + 1310720);
    unsigned short* Xf   = (unsigned short*)(ws + 11796480);
    unsigned short* Part = (unsigned short*)(ws + 24379392);

    prep_kernel<<<512 + NUM_Q / 128, 256, 0, stream>>>(x, query, Wk, Af, Xf, Qh);
    flash_kernel<<<(NUM_Q / 256) * NS, 256, 0, stream>>>(Qh, Af, Xf, Part);
    combine_kernel<<<NUM_Q / 2, 256, 0, stream>>>(Part, out);
}